// Round 2
// baseline (1236.209 us; speedup 1.0000x reference)
//
#include <hip/hip_runtime.h>

#define FEAT 128
#define U 8

typedef float v4f __attribute__((ext_vector_type(4)));

// Zero-fill d_out (harness re-poisons it to 0xAA before every timed launch).
__global__ __launch_bounds__(256) void zero_out_kernel(float* __restrict__ out, int n) {
    int i = blockIdx.x * blockDim.x + threadIdx.x;
    if (i < n) out[i] = 0.0f;
}

// Reduce acc0+acc1 across the 32-lane group and atomically add into out[cur].
#define FLUSH() do {                                                    \
    float r = acc0 + acc1;                                              \
    _Pragma("unroll")                                                   \
    for (int off = 16; off; off >>= 1) r += __shfl_xor(r, off);         \
    if (lane == 0) atomicAdd(&out[cur], r);                             \
    acc0 = 0.0f; acc1 = 0.0f;                                           \
} while (0)

// One 32-lane group per contiguous chunk of atoms.
// lane l loads float4 f[atom][4l..4l+3] -> 512B coalesced per group.
// Batched U=8: issue 8 independent f-loads (addresses independent of seg),
// then ONE group-uniform segment check (ids sorted: seg[a+U-1]==cur means the
// whole batch stays in the current segment -> branch-free accumulate).
__global__ __launch_bounds__(256, 4) void atomwise_readout_kernel(
    const float* __restrict__ f,
    const int*   __restrict__ seg,
    const float* __restrict__ w,
    float*       __restrict__ out,
    int n_atoms, int chunk) {

    const int tid   = blockIdx.x * blockDim.x + threadIdx.x;
    const int group = tid >> 5;       // 32 lanes per atom-group
    const int lane  = tid & 31;

    long start = (long)group * chunk;
    if (start >= n_atoms) return;
    long end = start + chunk;
    if (end > n_atoms) end = n_atoms;

    // w_e: 128 floats; lane l holds w[4l..4l+3]
    const v4f w4 = ((const v4f*)w)[lane];

    float acc0 = 0.0f, acc1 = 0.0f;
    int cur = seg[start];

    const v4f* fp = (const v4f*)(f + (size_t)start * FEAT) + lane;
    long a = start;

    // -------- batched main loop --------
    for (; a + U <= end; a += U) {
        // group-uniform check load first (its wait overlaps the f loads)
        const int sLast = seg[a + U - 1];

        // 8 independent 512B group-loads in flight
        v4f v[U];
        #pragma unroll
        for (int i = 0; i < U; ++i)
            v[i] = __builtin_nontemporal_load(fp + (size_t)i * (FEAT / 4));
        fp += (size_t)U * (FEAT / 4);

        if (sLast == cur) {
            // fast path: whole batch in current segment (sorted ids)
            #pragma unroll
            for (int i = 0; i < U; i += 2) {
                acc0 += v[i].x   * w4.x + v[i].y   * w4.y + v[i].z   * w4.z + v[i].w   * w4.w;
                acc1 += v[i+1].x * w4.x + v[i+1].y * w4.y + v[i+1].z * w4.z + v[i+1].w * w4.w;
            }
        } else {
            // rare: batch contains >=1 transition; per-atom using already-loaded v[i]
            #pragma unroll
            for (int i = 0; i < U; ++i) {
                const int s = seg[a + i];
                if (s != cur) { FLUSH(); cur = s; }
                acc0 += v[i].x * w4.x + v[i].y * w4.y + v[i].z * w4.z + v[i].w * w4.w;
            }
        }
    }

    // -------- tail (< U atoms) --------
    for (; a < end; ++a) {
        const int s = seg[a];
        if (s != cur) { FLUSH(); cur = s; }
        const v4f v = __builtin_nontemporal_load(fp);
        fp += FEAT / 4;
        acc0 += v.x * w4.x + v.y * w4.y + v.z * w4.z + v.w * w4.w;
    }

    FLUSH();
}

extern "C" void kernel_launch(void* const* d_in, const int* in_sizes, int n_in,
                              void* d_out, int out_size, void* d_ws, size_t ws_size,
                              hipStream_t stream) {
    const float* f   = (const float*)d_in[0];   // [n_atoms, 128] fp32
    const int*   seg = (const int*)d_in[1];     // [n_atoms] sorted int32
    // d_in[2] is n_graphs (scalar on device) -- out_size gives it on host
    const float* w   = (const float*)d_in[3];   // [128, 1] fp32
    float* out = (float*)d_out;

    const int n_atoms = in_sizes[1];

    zero_out_kernel<<<(out_size + 255) / 256, 256, 0, stream>>>(out, out_size);

    // ~16K groups -> chunk ~123 atoms; 8 groups per 256-thread block.
    const int target_groups = 16384;
    int chunk = (n_atoms + target_groups - 1) / target_groups;
    if (chunk < 1) chunk = 1;
    const int n_groups = (n_atoms + chunk - 1) / chunk;
    const int n_blocks = (n_groups + 7) / 8;

    atomwise_readout_kernel<<<n_blocks, 256, 0, stream>>>(f, seg, w, out, n_atoms, chunk);
}